// Round 4
// baseline (621.291 us; speedup 1.0000x reference)
//
#include <hip/hip_runtime.h>

#define N_NODES 100000
#define DEG 16
#define DIM 128
#define E_EDGES 1600000
#define NTILES 1563          // ceil(100000/64)
#define T8 196               // ceil(NTILES/8)
#define DGRID (T8 * 4 * 8)   // 6272 (some inert)
#define CHUNKS 1563          // ceil(100000/64) node-chunks for sharded aggr
#define LSTR 136             // LDS row stride in shorts (16B-aligned, conflict-light)

typedef short bf16x8 __attribute__((ext_vector_type(8)));
typedef float f32x4 __attribute__((ext_vector_type(4)));

__device__ __forceinline__ unsigned short f2bf(float f) {
    unsigned int u = __builtin_bit_cast(unsigned int, f);
    u = (u + 0x7fffu + ((u >> 16) & 1u)) >> 16;
    return (unsigned short)u;
}
__device__ __forceinline__ float bf2f(unsigned short h) {
    unsigned int u = ((unsigned int)h) << 16;
    return __builtin_bit_cast(float, u);
}
__device__ __forceinline__ bf16x8 pack_bf16x8(float4 lo, float4 hi) {
    bf16x8 f;
    f[0] = (short)f2bf(lo.x); f[1] = (short)f2bf(lo.y);
    f[2] = (short)f2bf(lo.z); f[3] = (short)f2bf(lo.w);
    f[4] = (short)f2bf(hi.x); f[5] = (short)f2bf(hi.y);
    f[6] = (short)f2bf(hi.z); f[7] = (short)f2bf(hi.w);
    return f;
}

// ---------------------------------------------------------------------------
// prep: cast W_W1|W_U1 -> Wc1 (256x128 bf16), W_W2|W_U2 -> Wc2
// ---------------------------------------------------------------------------
__global__ __launch_bounds__(256) void prep_w(
    const float* __restrict__ W_W1, const float* __restrict__ W_U1,
    const float* __restrict__ W_W2, const float* __restrict__ W_U2,
    unsigned short* __restrict__ Wc1, unsigned short* __restrict__ Wc2)
{
    int idx = blockIdx.x * 256 + threadIdx.x;      // 0..65535
    int half = idx & 32767;
    const float* src = (idx < 32768)
        ? (half < 16384 ? W_W1 + half : W_U1 + half - 16384)
        : (half < 16384 ? W_W2 + half : W_U2 + half - 16384);
    unsigned short* dst = (idx < 32768) ? Wc1 + half : Wc2 + half;
    *dst = f2bf(*src);
}

// ---------------------------------------------------------------------------
// dense1: z = h @ W_W^T, zi = h @ W_U^T (bf16 out) + score partials.
// f32 input (attr). Block = 64 nodes x 64 output cols, XCD-swizzled.
// ---------------------------------------------------------------------------
__global__ __launch_bounds__(256) void dense_tile(
    const float* __restrict__ hsrc,          // N x 128 f32
    const unsigned short* __restrict__ Wc,   // 256 x 128 bf16
    const float* __restrict__ W_a,           // 257 f32
    unsigned short* __restrict__ z,
    unsigned short* __restrict__ zi,
    float* __restrict__ s_src0, float* __restrict__ s_src1,
    float* __restrict__ s_dst0, float* __restrict__ s_dst1)
{
    __shared__ unsigned short Wt[64 * LSTR];
    __shared__ unsigned short Ht[64 * LSTR];

    const int bid = blockIdx.x;
    const int xcd = bid & 7;
    const int q = bid >> 3;
    const int cb = q & 3;
    const int tile = (q >> 2) * 8 + xcd;
    if (tile >= NTILES) return;
    const int nodebase = tile * 64;
    const int t = threadIdx.x;

    {
        int r = t >> 2, c0 = (t & 3) * 32;
        const unsigned short* src = Wc + (size_t)(cb * 64 + r) * DIM + c0;
        unsigned short* dst = Wt + r * LSTR + c0;
#pragma unroll
        for (int i = 0; i < 4; i++)
            *(uint4*)(dst + i * 8) = *(const uint4*)(src + i * 8);
    }
    {
        int r = t >> 2, c0 = (t & 3) * 32;
        int node = nodebase + r;
        unsigned short* dst = Ht + r * LSTR + c0;
        float4 v[8];
#pragma unroll
        for (int i = 0; i < 8; i++) v[i] = make_float4(0.f, 0.f, 0.f, 0.f);
        if (node < N_NODES) {
            const float* src = hsrc + (size_t)node * DIM + c0;
#pragma unroll
            for (int i = 0; i < 8; i++) v[i] = *(const float4*)(src + i * 4);
        }
#pragma unroll
        for (int i = 0; i < 4; i++)
            *(bf16x8*)(dst + i * 8) = pack_bf16x8(v[2 * i], v[2 * i + 1]);
    }
    __syncthreads();

    const int wave = t >> 6;
    const int lane = t & 63;
    const int n16 = lane & 15;
    const int quad = lane >> 4;
    const int node = nodebase + wave * 16 + n16;

    bf16x8 hfrag[4];
    const unsigned short* hrow = Ht + (wave * 16 + n16) * LSTR + quad * 8;
#pragma unroll
    for (int ks = 0; ks < 4; ks++)
        hfrag[ks] = *(const bf16x8*)(hrow + ks * 32);

    f32x4 acc[4];
#pragma unroll
    for (int ct = 0; ct < 4; ct++) {
        const unsigned short* wrow = Wt + (ct * 16 + n16) * LSTR + quad * 8;
        f32x4 a = {0.f, 0.f, 0.f, 0.f};
#pragma unroll
        for (int ks = 0; ks < 4; ks++)
            a = __builtin_amdgcn_mfma_f32_16x16x32_bf16(
                    *(const bf16x8*)(wrow + ks * 32), hfrag[ks], a, 0, 0, 0);
        acc[ct] = a;
    }

    if (node < N_NODES) {
        unsigned short* zout = (cb < 2 ? z : zi);
        unsigned short* orow = zout + (size_t)node * DIM + (cb & 1) * 64 + quad * 4;
#pragma unroll
        for (int ct = 0; ct < 4; ct++) {
            uint2 pk;
            pk.x = (unsigned int)f2bf(acc[ct][0]) | ((unsigned int)f2bf(acc[ct][1]) << 16);
            pk.y = (unsigned int)f2bf(acc[ct][2]) | ((unsigned int)f2bf(acc[ct][3]) << 16);
            *(uint2*)(orow + ct * 16) = pk;
        }
    }

    if (cb < 2) {
        float ps = 0.f, pd = 0.f;
#pragma unroll
        for (int ct = 0; ct < 4; ct++) {
            float4 as = *(const float4*)(W_a + cb * 64 + ct * 16 + quad * 4);
            float4 ad = *(const float4*)(W_a + DIM + cb * 64 + ct * 16 + quad * 4);
            ps += acc[ct][0] * as.x + acc[ct][1] * as.y
                + acc[ct][2] * as.z + acc[ct][3] * as.w;
            pd += acc[ct][0] * ad.x + acc[ct][1] * ad.y
                + acc[ct][2] * ad.z + acc[ct][3] * ad.w;
        }
        ps += __shfl_xor(ps, 16); ps += __shfl_xor(ps, 32);
        pd += __shfl_xor(pd, 16); pd += __shfl_xor(pd, 32);
        if (lane < 16 && node < N_NODES) {
            (cb == 0 ? s_src0 : s_src1)[node] = ps;
            (cb == 0 ? s_dst0 : s_dst1)[node] = pd;
        }
    }
}

// ---------------------------------------------------------------------------
// dense_b: same as dense_tile but bf16 input (h1). No f32->bf16 convert on
// the staging path.
// ---------------------------------------------------------------------------
__global__ __launch_bounds__(256) void dense_tile_b(
    const unsigned short* __restrict__ hsrc, // N x 128 bf16
    const unsigned short* __restrict__ Wc,   // 256 x 128 bf16
    const float* __restrict__ W_a,
    unsigned short* __restrict__ z,
    unsigned short* __restrict__ zi,
    float* __restrict__ s_src0, float* __restrict__ s_src1,
    float* __restrict__ s_dst0, float* __restrict__ s_dst1)
{
    __shared__ unsigned short Wt[64 * LSTR];
    __shared__ unsigned short Ht[64 * LSTR];

    const int bid = blockIdx.x;
    const int xcd = bid & 7;
    const int q = bid >> 3;
    const int cb = q & 3;
    const int tile = (q >> 2) * 8 + xcd;
    if (tile >= NTILES) return;
    const int nodebase = tile * 64;
    const int t = threadIdx.x;

    {
        int r = t >> 2, c0 = (t & 3) * 32;
        const unsigned short* src = Wc + (size_t)(cb * 64 + r) * DIM + c0;
        unsigned short* dst = Wt + r * LSTR + c0;
#pragma unroll
        for (int i = 0; i < 4; i++)
            *(uint4*)(dst + i * 8) = *(const uint4*)(src + i * 8);
    }
    {
        int r = t >> 2, c0 = (t & 3) * 32;
        int node = nodebase + r;
        unsigned short* dst = Ht + r * LSTR + c0;
        if (node < N_NODES) {
            const unsigned short* src = hsrc + (size_t)node * DIM + c0;
#pragma unroll
            for (int i = 0; i < 4; i++)
                *(uint4*)(dst + i * 8) = *(const uint4*)(src + i * 8);
        } else {
            uint4 zr4 = make_uint4(0, 0, 0, 0);
#pragma unroll
            for (int i = 0; i < 4; i++) *(uint4*)(dst + i * 8) = zr4;
        }
    }
    __syncthreads();

    const int wave = t >> 6;
    const int lane = t & 63;
    const int n16 = lane & 15;
    const int quad = lane >> 4;
    const int node = nodebase + wave * 16 + n16;

    bf16x8 hfrag[4];
    const unsigned short* hrow = Ht + (wave * 16 + n16) * LSTR + quad * 8;
#pragma unroll
    for (int ks = 0; ks < 4; ks++)
        hfrag[ks] = *(const bf16x8*)(hrow + ks * 32);

    f32x4 acc[4];
#pragma unroll
    for (int ct = 0; ct < 4; ct++) {
        const unsigned short* wrow = Wt + (ct * 16 + n16) * LSTR + quad * 8;
        f32x4 a = {0.f, 0.f, 0.f, 0.f};
#pragma unroll
        for (int ks = 0; ks < 4; ks++)
            a = __builtin_amdgcn_mfma_f32_16x16x32_bf16(
                    *(const bf16x8*)(wrow + ks * 32), hfrag[ks], a, 0, 0, 0);
        acc[ct] = a;
    }

    if (node < N_NODES) {
        unsigned short* zout = (cb < 2 ? z : zi);
        unsigned short* orow = zout + (size_t)node * DIM + (cb & 1) * 64 + quad * 4;
#pragma unroll
        for (int ct = 0; ct < 4; ct++) {
            uint2 pk;
            pk.x = (unsigned int)f2bf(acc[ct][0]) | ((unsigned int)f2bf(acc[ct][1]) << 16);
            pk.y = (unsigned int)f2bf(acc[ct][2]) | ((unsigned int)f2bf(acc[ct][3]) << 16);
            *(uint2*)(orow + ct * 16) = pk;
        }
    }

    if (cb < 2) {
        float ps = 0.f, pd = 0.f;
#pragma unroll
        for (int ct = 0; ct < 4; ct++) {
            float4 as = *(const float4*)(W_a + cb * 64 + ct * 16 + quad * 4);
            float4 ad = *(const float4*)(W_a + DIM + cb * 64 + ct * 16 + quad * 4);
            ps += acc[ct][0] * as.x + acc[ct][1] * as.y
                + acc[ct][2] * as.z + acc[ct][3] * as.w;
            pd += acc[ct][0] * ad.x + acc[ct][1] * ad.y
                + acc[ct][2] * ad.z + acc[ct][3] * ad.w;
        }
        ps += __shfl_xor(ps, 16); ps += __shfl_xor(ps, 32);
        pd += __shfl_xor(pd, 16); pd += __shfl_xor(pd, 32);
        if (lane < 16 && node < N_NODES) {
            (cb == 0 ? s_src0 : s_src1)[node] = ps;
            (cb == 0 ? s_dst0 : s_dst1)[node] = pd;
        }
    }
}

// ---------------------------------------------------------------------------
// alpha_k: per-edge softmax coefficients -> alpha[E] f32.
// grid 6250 x 256 = exactly E threads; 16-lane group = one node's edges.
// ---------------------------------------------------------------------------
__global__ __launch_bounds__(256) void alpha_k(
    const float* __restrict__ s_src0, const float* __restrict__ s_src1,
    const float* __restrict__ s_dst0, const float* __restrict__ s_dst1,
    const float* __restrict__ edge_d,
    const int* __restrict__ edge_src,
    const float* __restrict__ W_V,
    const float* __restrict__ W_a,
    float* __restrict__ alpha)
{
    const int e = blockIdx.x * 256 + threadIdx.x;   // 0..E-1
    const int node = e >> 4;                         // edge_dst
    int   s  = edge_src[e];
    float ed = edge_d[e];
    float coef = W_V[0] * W_a[2 * DIM];
    float x = (s_src0[s] + s_src1[s]) + (s_dst0[node] + s_dst1[node]) + ed * coef;
    x = x > 0.f ? x : 0.01f * x;
    float m = x;
    m = fmaxf(m, __shfl_xor(m, 1));
    m = fmaxf(m, __shfl_xor(m, 2));
    m = fmaxf(m, __shfl_xor(m, 4));
    m = fmaxf(m, __shfl_xor(m, 8));
    float ex = __expf(x - m);
    float d = ex;
    d += __shfl_xor(d, 1); d += __shfl_xor(d, 2);
    d += __shfl_xor(d, 4); d += __shfl_xor(d, 8);
    alpha[e] = ex / d;
}

// ---------------------------------------------------------------------------
// aggr_slice: XCD-sharded softmax-aggregate.
// slice = bid & 7 -> all blocks of a slice land on ONE XCD (round-robin
// dispatch), so the slice's gather working set (100k x 16 cols bf16 = 3.2 MB)
// is L2-resident on that XCD. Block = 64 nodes; thread = (node, 4-col group).
// Per thread: 16 independent 8B L2-hit gathers, FMA-accumulated.
// Writes h1 slice (bf16).
// ---------------------------------------------------------------------------
__global__ __launch_bounds__(256) void aggr_slice(
    const unsigned short* __restrict__ z,    // N x 128 bf16
    const unsigned short* __restrict__ zi,   // N x 128 bf16
    const float* __restrict__ alpha,         // E f32
    const int* __restrict__ edge_src,
    unsigned short* __restrict__ hout)       // N x 128 bf16
{
    __shared__ float alpha_s[64][17];
    __shared__ int   src_s[64][17];

    const int bid = blockIdx.x;
    const int slice = bid & 7;
    const int chunk = bid >> 3;
    const int t = threadIdx.x;
    const int nodebase = chunk * 64;

    // stage 64 nodes x 16 edges of (alpha, src)
    {
        int idx = t * 4;                     // 0..1023
        int e0 = nodebase * DEG + idx;
        int nl = idx >> 4, j0 = idx & 15;
        float4 a4 = make_float4(0.f, 0.f, 0.f, 0.f);
        int4   s4 = make_int4(0, 0, 0, 0);
        if (e0 < E_EDGES) {
            a4 = *(const float4*)(alpha + e0);
            s4 = *(const int4*)(edge_src + e0);
        }
        alpha_s[nl][j0 + 0] = a4.x; alpha_s[nl][j0 + 1] = a4.y;
        alpha_s[nl][j0 + 2] = a4.z; alpha_s[nl][j0 + 3] = a4.w;
        src_s[nl][j0 + 0] = s4.x; src_s[nl][j0 + 1] = s4.y;
        src_s[nl][j0 + 2] = s4.z; src_s[nl][j0 + 3] = s4.w;
    }
    __syncthreads();

    const int nl  = t >> 2;                  // 0..63
    const int col = slice * 16 + (t & 3) * 4;
    const int node = nodebase + nl;
    const unsigned short* zcol = z + col;

    float a0 = 0.f, a1 = 0.f, a2 = 0.f, a3 = 0.f;
#pragma unroll
    for (int e = 0; e < DEG; e++) {
        int   sj = src_s[nl][e];
        float a  = alpha_s[nl][e];
        uint2 r = *(const uint2*)(zcol + (size_t)sj * DIM);
        a0 += a * bf2f((unsigned short)(r.x & 0xffff));
        a1 += a * bf2f((unsigned short)(r.x >> 16));
        a2 += a * bf2f((unsigned short)(r.y & 0xffff));
        a3 += a * bf2f((unsigned short)(r.y >> 16));
    }

    if (node < N_NODES) {
        uint2 zr = *(const uint2*)(zi + (size_t)node * DIM + col);
        float v0 = fmaxf(bf2f((unsigned short)(zr.x & 0xffff)) + a0, 0.f);
        float v1 = fmaxf(bf2f((unsigned short)(zr.x >> 16)) + a1, 0.f);
        float v2 = fmaxf(bf2f((unsigned short)(zr.y & 0xffff)) + a2, 0.f);
        float v3 = fmaxf(bf2f((unsigned short)(zr.y >> 16)) + a3, 0.f);
        uint2 pk;
        pk.x = (unsigned int)f2bf(v0) | ((unsigned int)f2bf(v1) << 16);
        pk.y = (unsigned int)f2bf(v2) | ((unsigned int)f2bf(v3) << 16);
        *(uint2*)(hout + (size_t)node * DIM + col) = pk;
    }
}

// ---------------------------------------------------------------------------
// aggr_slice_final: same sharded aggregate, f32 output (layer 2).
// ---------------------------------------------------------------------------
__global__ __launch_bounds__(256) void aggr_slice_final(
    const unsigned short* __restrict__ z,    // z2
    const unsigned short* __restrict__ zi,   // zi2
    const float* __restrict__ alpha,
    const int* __restrict__ edge_src,
    float* __restrict__ out_f32)
{
    __shared__ float alpha_s[64][17];
    __shared__ int   src_s[64][17];

    const int bid = blockIdx.x;
    const int slice = bid & 7;
    const int chunk = bid >> 3;
    const int t = threadIdx.x;
    const int nodebase = chunk * 64;

    {
        int idx = t * 4;
        int e0 = nodebase * DEG + idx;
        int nl = idx >> 4, j0 = idx & 15;
        float4 a4 = make_float4(0.f, 0.f, 0.f, 0.f);
        int4   s4 = make_int4(0, 0, 0, 0);
        if (e0 < E_EDGES) {
            a4 = *(const float4*)(alpha + e0);
            s4 = *(const int4*)(edge_src + e0);
        }
        alpha_s[nl][j0 + 0] = a4.x; alpha_s[nl][j0 + 1] = a4.y;
        alpha_s[nl][j0 + 2] = a4.z; alpha_s[nl][j0 + 3] = a4.w;
        src_s[nl][j0 + 0] = s4.x; src_s[nl][j0 + 1] = s4.y;
        src_s[nl][j0 + 2] = s4.z; src_s[nl][j0 + 3] = s4.w;
    }
    __syncthreads();

    const int nl  = t >> 2;
    const int col = slice * 16 + (t & 3) * 4;
    const int node = nodebase + nl;
    const unsigned short* zcol = z + col;

    float a0 = 0.f, a1 = 0.f, a2 = 0.f, a3 = 0.f;
#pragma unroll
    for (int e = 0; e < DEG; e++) {
        int   sj = src_s[nl][e];
        float a  = alpha_s[nl][e];
        uint2 r = *(const uint2*)(zcol + (size_t)sj * DIM);
        a0 += a * bf2f((unsigned short)(r.x & 0xffff));
        a1 += a * bf2f((unsigned short)(r.x >> 16));
        a2 += a * bf2f((unsigned short)(r.y & 0xffff));
        a3 += a * bf2f((unsigned short)(r.y >> 16));
    }

    if (node < N_NODES) {
        uint2 zr = *(const uint2*)(zi + (size_t)node * DIM + col);
        f32x4 o;
        o[0] = fmaxf(bf2f((unsigned short)(zr.x & 0xffff)) + a0, 0.f);
        o[1] = fmaxf(bf2f((unsigned short)(zr.x >> 16)) + a1, 0.f);
        o[2] = fmaxf(bf2f((unsigned short)(zr.y & 0xffff)) + a2, 0.f);
        o[3] = fmaxf(bf2f((unsigned short)(zr.y >> 16)) + a3, 0.f);
        *(f32x4*)(out_f32 + (size_t)node * DIM + col) = o;
    }
}

// ---------------------------------------------------------------------------
extern "C" void kernel_launch(void* const* d_in, const int* in_sizes, int n_in,
                              void* d_out, int out_size, void* d_ws, size_t ws_size,
                              hipStream_t stream) {
    const float* attr     = (const float*)d_in[0];
    const float* edge_d   = (const float*)d_in[1];
    const float* W_V1     = (const float*)d_in[2];
    const float* W_W1     = (const float*)d_in[3];
    const float* W_U1     = (const float*)d_in[4];
    const float* W_a1     = (const float*)d_in[5];
    const float* W_V2     = (const float*)d_in[6];
    const float* W_W2     = (const float*)d_in[7];
    const float* W_U2     = (const float*)d_in[8];
    const float* W_a2     = (const float*)d_in[9];
    const int*   edge_src = (const int*)d_in[10];

    float* out = (float*)d_out;

    char* ws = (char*)d_ws;
    unsigned short* z1    = (unsigned short*)ws;                       // 25.6 MB
    unsigned short* zi1   = (unsigned short*)(ws + 26u * 1024 * 1024); // 25.6 MB
    unsigned short* h1    = (unsigned short*)(ws + 52u * 1024 * 1024); // 25.6 MB
    unsigned short* Wc1   = (unsigned short*)(ws + 78u * 1024 * 1024);
    unsigned short* Wc2   = (unsigned short*)(ws + 79u * 1024 * 1024);
    float* s_src0         = (float*)(ws + 80u * 1024 * 1024);
    float* s_src1         = (float*)(ws + 81u * 1024 * 1024);
    float* s_dst0         = (float*)(ws + 82u * 1024 * 1024);
    float* s_dst1         = (float*)(ws + 83u * 1024 * 1024);
    float* alphaA         = (float*)(ws + 84u * 1024 * 1024);          // 6.4 MB
    // z2/zi2 overlay z1/zi1 (strictly sequential dependencies)
    unsigned short* z2  = z1;
    unsigned short* zi2 = zi1;

    prep_w<<<256, 256, 0, stream>>>(W_W1, W_U1, W_W2, W_U2, Wc1, Wc2);

    // ---- layer 1 ----
    dense_tile<<<DGRID, 256, 0, stream>>>(attr, Wc1, W_a1, z1, zi1,
                                          s_src0, s_src1, s_dst0, s_dst1);

    alpha_k<<<6250, 256, 0, stream>>>(s_src0, s_src1, s_dst0, s_dst1,
                                      edge_d, edge_src, W_V1, W_a1, alphaA);

    aggr_slice<<<CHUNKS * 8, 256, 0, stream>>>(z1, zi1, alphaA, edge_src, h1);

    // ---- layer 2 ----
    dense_tile_b<<<DGRID, 256, 0, stream>>>(h1, Wc2, W_a2, z2, zi2,
                                            s_src0, s_src1, s_dst0, s_dst1);

    alpha_k<<<6250, 256, 0, stream>>>(s_src0, s_src1, s_dst0, s_dst1,
                                      edge_d, edge_src, W_V2, W_a2, alphaA);

    aggr_slice_final<<<CHUNKS * 8, 256, 0, stream>>>(z2, zi2, alphaA, edge_src, out);
}

// Round 5
// 355.531 us; speedup vs baseline: 1.7475x; 1.7475x over previous
//
#include <hip/hip_runtime.h>

#define N_NODES 100000
#define DEG 16
#define DIM 128
#define E_EDGES 1600000
#define NTILES 1563          // ceil(100000/64)
#define T8 196               // ceil(NTILES/8)
#define DGRID (T8 * 4 * 8)   // 6272 (some inert)
#define LSTR 136             // LDS row stride in shorts (16B-aligned, conflict-light)

typedef short bf16x8 __attribute__((ext_vector_type(8)));
typedef float f32x4 __attribute__((ext_vector_type(4)));

__device__ __forceinline__ unsigned short f2bf(float f) {
    unsigned int u = __builtin_bit_cast(unsigned int, f);
    u = (u + 0x7fffu + ((u >> 16) & 1u)) >> 16;
    return (unsigned short)u;
}
__device__ __forceinline__ float bf2f(unsigned short h) {
    unsigned int u = ((unsigned int)h) << 16;
    return __builtin_bit_cast(float, u);
}
__device__ __forceinline__ bf16x8 pack_bf16x8(float4 lo, float4 hi) {
    bf16x8 f;
    f[0] = (short)f2bf(lo.x); f[1] = (short)f2bf(lo.y);
    f[2] = (short)f2bf(lo.z); f[3] = (short)f2bf(lo.w);
    f[4] = (short)f2bf(hi.x); f[5] = (short)f2bf(hi.y);
    f[6] = (short)f2bf(hi.z); f[7] = (short)f2bf(hi.w);
    return f;
}

// ---------------------------------------------------------------------------
// prep: cast W_W1|W_U1 -> Wc1 (256x128 bf16), W_W2|W_U2 -> Wc2
// ---------------------------------------------------------------------------
__global__ __launch_bounds__(256) void prep_w(
    const float* __restrict__ W_W1, const float* __restrict__ W_U1,
    const float* __restrict__ W_W2, const float* __restrict__ W_U2,
    unsigned short* __restrict__ Wc1, unsigned short* __restrict__ Wc2)
{
    int idx = blockIdx.x * 256 + threadIdx.x;      // 0..65535
    int half = idx & 32767;
    const float* src = (idx < 32768)
        ? (half < 16384 ? W_W1 + half : W_U1 + half - 16384)
        : (half < 16384 ? W_W2 + half : W_U2 + half - 16384);
    unsigned short* dst = (idx < 32768) ? Wc1 + half : Wc2 + half;
    *dst = f2bf(*src);
}

// ---------------------------------------------------------------------------
// dense1: z = h @ W_W^T, zi = h @ W_U^T (bf16 out) + score partials.
// f32 input (attr). Block = 64 nodes x 64 output cols, XCD-swizzled.
// ---------------------------------------------------------------------------
__global__ __launch_bounds__(256) void dense_tile(
    const float* __restrict__ hsrc,          // N x 128 f32
    const unsigned short* __restrict__ Wc,   // 256 x 128 bf16
    const float* __restrict__ W_a,           // 257 f32
    unsigned short* __restrict__ z,
    unsigned short* __restrict__ zi,
    float* __restrict__ s_src0, float* __restrict__ s_src1,
    float* __restrict__ s_dst0, float* __restrict__ s_dst1)
{
    __shared__ unsigned short Wt[64 * LSTR];
    __shared__ unsigned short Ht[64 * LSTR];

    const int bid = blockIdx.x;
    const int xcd = bid & 7;
    const int q = bid >> 3;
    const int cb = q & 3;
    const int tile = (q >> 2) * 8 + xcd;
    if (tile >= NTILES) return;
    const int nodebase = tile * 64;
    const int t = threadIdx.x;

    {
        int r = t >> 2, c0 = (t & 3) * 32;
        const unsigned short* src = Wc + (size_t)(cb * 64 + r) * DIM + c0;
        unsigned short* dst = Wt + r * LSTR + c0;
#pragma unroll
        for (int i = 0; i < 4; i++)
            *(uint4*)(dst + i * 8) = *(const uint4*)(src + i * 8);
    }
    {
        int r = t >> 2, c0 = (t & 3) * 32;
        int node = nodebase + r;
        unsigned short* dst = Ht + r * LSTR + c0;
        float4 v[8];
#pragma unroll
        for (int i = 0; i < 8; i++) v[i] = make_float4(0.f, 0.f, 0.f, 0.f);
        if (node < N_NODES) {
            const float* src = hsrc + (size_t)node * DIM + c0;
#pragma unroll
            for (int i = 0; i < 8; i++) v[i] = *(const float4*)(src + i * 4);
        }
#pragma unroll
        for (int i = 0; i < 4; i++)
            *(bf16x8*)(dst + i * 8) = pack_bf16x8(v[2 * i], v[2 * i + 1]);
    }
    __syncthreads();

    const int wave = t >> 6;
    const int lane = t & 63;
    const int n16 = lane & 15;
    const int quad = lane >> 4;
    const int node = nodebase + wave * 16 + n16;

    bf16x8 hfrag[4];
    const unsigned short* hrow = Ht + (wave * 16 + n16) * LSTR + quad * 8;
#pragma unroll
    for (int ks = 0; ks < 4; ks++)
        hfrag[ks] = *(const bf16x8*)(hrow + ks * 32);

    f32x4 acc[4];
#pragma unroll
    for (int ct = 0; ct < 4; ct++) {
        const unsigned short* wrow = Wt + (ct * 16 + n16) * LSTR + quad * 8;
        f32x4 a = {0.f, 0.f, 0.f, 0.f};
#pragma unroll
        for (int ks = 0; ks < 4; ks++)
            a = __builtin_amdgcn_mfma_f32_16x16x32_bf16(
                    *(const bf16x8*)(wrow + ks * 32), hfrag[ks], a, 0, 0, 0);
        acc[ct] = a;
    }

    if (node < N_NODES) {
        unsigned short* zout = (cb < 2 ? z : zi);
        unsigned short* orow = zout + (size_t)node * DIM + (cb & 1) * 64 + quad * 4;
#pragma unroll
        for (int ct = 0; ct < 4; ct++) {
            uint2 pk;
            pk.x = (unsigned int)f2bf(acc[ct][0]) | ((unsigned int)f2bf(acc[ct][1]) << 16);
            pk.y = (unsigned int)f2bf(acc[ct][2]) | ((unsigned int)f2bf(acc[ct][3]) << 16);
            *(uint2*)(orow + ct * 16) = pk;
        }
    }

    if (cb < 2) {
        float ps = 0.f, pd = 0.f;
#pragma unroll
        for (int ct = 0; ct < 4; ct++) {
            float4 as = *(const float4*)(W_a + cb * 64 + ct * 16 + quad * 4);
            float4 ad = *(const float4*)(W_a + DIM + cb * 64 + ct * 16 + quad * 4);
            ps += acc[ct][0] * as.x + acc[ct][1] * as.y
                + acc[ct][2] * as.z + acc[ct][3] * as.w;
            pd += acc[ct][0] * ad.x + acc[ct][1] * ad.y
                + acc[ct][2] * ad.z + acc[ct][3] * ad.w;
        }
        ps += __shfl_xor(ps, 16); ps += __shfl_xor(ps, 32);
        pd += __shfl_xor(pd, 16); pd += __shfl_xor(pd, 32);
        if (lane < 16 && node < N_NODES) {
            (cb == 0 ? s_src0 : s_src1)[node] = ps;
            (cb == 0 ? s_dst0 : s_dst1)[node] = pd;
        }
    }
}

// ---------------------------------------------------------------------------
// dense_b: same as dense_tile but bf16 input (h1).
// ---------------------------------------------------------------------------
__global__ __launch_bounds__(256) void dense_tile_b(
    const unsigned short* __restrict__ hsrc, // N x 128 bf16
    const unsigned short* __restrict__ Wc,   // 256 x 128 bf16
    const float* __restrict__ W_a,
    unsigned short* __restrict__ z,
    unsigned short* __restrict__ zi,
    float* __restrict__ s_src0, float* __restrict__ s_src1,
    float* __restrict__ s_dst0, float* __restrict__ s_dst1)
{
    __shared__ unsigned short Wt[64 * LSTR];
    __shared__ unsigned short Ht[64 * LSTR];

    const int bid = blockIdx.x;
    const int xcd = bid & 7;
    const int q = bid >> 3;
    const int cb = q & 3;
    const int tile = (q >> 2) * 8 + xcd;
    if (tile >= NTILES) return;
    const int nodebase = tile * 64;
    const int t = threadIdx.x;

    {
        int r = t >> 2, c0 = (t & 3) * 32;
        const unsigned short* src = Wc + (size_t)(cb * 64 + r) * DIM + c0;
        unsigned short* dst = Wt + r * LSTR + c0;
#pragma unroll
        for (int i = 0; i < 4; i++)
            *(uint4*)(dst + i * 8) = *(const uint4*)(src + i * 8);
    }
    {
        int r = t >> 2, c0 = (t & 3) * 32;
        int node = nodebase + r;
        unsigned short* dst = Ht + r * LSTR + c0;
        if (node < N_NODES) {
            const unsigned short* src = hsrc + (size_t)node * DIM + c0;
#pragma unroll
            for (int i = 0; i < 4; i++)
                *(uint4*)(dst + i * 8) = *(const uint4*)(src + i * 8);
        } else {
            uint4 zr4 = make_uint4(0, 0, 0, 0);
#pragma unroll
            for (int i = 0; i < 4; i++) *(uint4*)(dst + i * 8) = zr4;
        }
    }
    __syncthreads();

    const int wave = t >> 6;
    const int lane = t & 63;
    const int n16 = lane & 15;
    const int quad = lane >> 4;
    const int node = nodebase + wave * 16 + n16;

    bf16x8 hfrag[4];
    const unsigned short* hrow = Ht + (wave * 16 + n16) * LSTR + quad * 8;
#pragma unroll
    for (int ks = 0; ks < 4; ks++)
        hfrag[ks] = *(const bf16x8*)(hrow + ks * 32);

    f32x4 acc[4];
#pragma unroll
    for (int ct = 0; ct < 4; ct++) {
        const unsigned short* wrow = Wt + (ct * 16 + n16) * LSTR + quad * 8;
        f32x4 a = {0.f, 0.f, 0.f, 0.f};
#pragma unroll
        for (int ks = 0; ks < 4; ks++)
            a = __builtin_amdgcn_mfma_f32_16x16x32_bf16(
                    *(const bf16x8*)(wrow + ks * 32), hfrag[ks], a, 0, 0, 0);
        acc[ct] = a;
    }

    if (node < N_NODES) {
        unsigned short* zout = (cb < 2 ? z : zi);
        unsigned short* orow = zout + (size_t)node * DIM + (cb & 1) * 64 + quad * 4;
#pragma unroll
        for (int ct = 0; ct < 4; ct++) {
            uint2 pk;
            pk.x = (unsigned int)f2bf(acc[ct][0]) | ((unsigned int)f2bf(acc[ct][1]) << 16);
            pk.y = (unsigned int)f2bf(acc[ct][2]) | ((unsigned int)f2bf(acc[ct][3]) << 16);
            *(uint2*)(orow + ct * 16) = pk;
        }
    }

    if (cb < 2) {
        float ps = 0.f, pd = 0.f;
#pragma unroll
        for (int ct = 0; ct < 4; ct++) {
            float4 as = *(const float4*)(W_a + cb * 64 + ct * 16 + quad * 4);
            float4 ad = *(const float4*)(W_a + DIM + cb * 64 + ct * 16 + quad * 4);
            ps += acc[ct][0] * as.x + acc[ct][1] * as.y
                + acc[ct][2] * as.z + acc[ct][3] * as.w;
            pd += acc[ct][0] * ad.x + acc[ct][1] * ad.y
                + acc[ct][2] * ad.z + acc[ct][3] * ad.w;
        }
        ps += __shfl_xor(ps, 16); ps += __shfl_xor(ps, 32);
        pd += __shfl_xor(pd, 16); pd += __shfl_xor(pd, 32);
        if (lane < 16 && node < N_NODES) {
            (cb == 0 ? s_src0 : s_src1)[node] = ps;
            (cb == 0 ? s_dst0 : s_dst1)[node] = pd;
        }
    }
}

// ---------------------------------------------------------------------------
// alpha_k: per-edge softmax coefficients -> alpha[E] f32.
// grid 6250 x 256 = exactly E threads; 16-lane group = one node's edges.
// ---------------------------------------------------------------------------
__global__ __launch_bounds__(256) void alpha_k(
    const float* __restrict__ s_src0, const float* __restrict__ s_src1,
    const float* __restrict__ s_dst0, const float* __restrict__ s_dst1,
    const float* __restrict__ edge_d,
    const int* __restrict__ edge_src,
    const float* __restrict__ W_V,
    const float* __restrict__ W_a,
    float* __restrict__ alpha)
{
    const int e = blockIdx.x * 256 + threadIdx.x;   // 0..E-1
    const int node = e >> 4;                         // edge_dst
    int   s  = edge_src[e];
    float ed = edge_d[e];
    float coef = W_V[0] * W_a[2 * DIM];
    float x = (s_src0[s] + s_src1[s]) + (s_dst0[node] + s_dst1[node]) + ed * coef;
    x = x > 0.f ? x : 0.01f * x;
    float m = x;
    m = fmaxf(m, __shfl_xor(m, 1));
    m = fmaxf(m, __shfl_xor(m, 2));
    m = fmaxf(m, __shfl_xor(m, 4));
    m = fmaxf(m, __shfl_xor(m, 8));
    float ex = __expf(x - m);
    float d = ex;
    d += __shfl_xor(d, 1); d += __shfl_xor(d, 2);
    d += __shfl_xor(d, 4); d += __shfl_xor(d, 8);
    alpha[e] = ex / d;
}

// ---------------------------------------------------------------------------
// aggr_row: full-row softmax-aggregate, round-4 concurrency structure.
// Block = 16 nodes x 16 col-groups (16B each). Stage 256 (alpha, src) pairs
// coalesced (one per thread), barrier, then 16 independent uint4 gathers per
// thread with immediate FMA accumulate. No scattered score loads, no shfl
// chains, lean VGPR -> high occupancy (round-4 profile) at the 212 MB
// compulsory-fetch addressing (round-3 profile).
// Writes h1 (bf16).
// ---------------------------------------------------------------------------
__global__ __launch_bounds__(256) void aggr_row(
    const unsigned short* __restrict__ z,    // N x 128 bf16
    const unsigned short* __restrict__ zi,   // N x 128 bf16
    const float* __restrict__ alpha,         // E f32
    const int* __restrict__ edge_src,
    unsigned short* __restrict__ hout)       // N x 128 bf16
{
    __shared__ float alpha_s[256];
    __shared__ int   src_s[256];

    const int t = threadIdx.x;
    const int base = blockIdx.x * 16;        // 16 nodes/block

    {
        int e0 = base * DEG + t;             // 256 consecutive edges
        alpha_s[t] = alpha[e0];
        src_s[t]   = edge_src[e0];
    }
    __syncthreads();

    const int nl = t >> 4;                   // node in block
    const int j  = t & 15;                   // col-group
    const int node = base + nl;
    const int c8 = j * 8;
    const unsigned short* zc = z + c8;

    float acc[8] = {};
#pragma unroll
    for (int e = 0; e < DEG; e++) {
        int   sj = src_s[nl * 16 + e];
        float a  = alpha_s[nl * 16 + e];
        uint4 r = *(const uint4*)(zc + (size_t)sj * DIM);
        acc[0] += a * bf2f((unsigned short)(r.x & 0xffff));
        acc[1] += a * bf2f((unsigned short)(r.x >> 16));
        acc[2] += a * bf2f((unsigned short)(r.y & 0xffff));
        acc[3] += a * bf2f((unsigned short)(r.y >> 16));
        acc[4] += a * bf2f((unsigned short)(r.z & 0xffff));
        acc[5] += a * bf2f((unsigned short)(r.z >> 16));
        acc[6] += a * bf2f((unsigned short)(r.w & 0xffff));
        acc[7] += a * bf2f((unsigned short)(r.w >> 16));
    }

    uint4 zr = *(const uint4*)(zi + (size_t)node * DIM + c8);
    float v[8];
    v[0] = fmaxf(bf2f((unsigned short)(zr.x & 0xffff)) + acc[0], 0.f);
    v[1] = fmaxf(bf2f((unsigned short)(zr.x >> 16)) + acc[1], 0.f);
    v[2] = fmaxf(bf2f((unsigned short)(zr.y & 0xffff)) + acc[2], 0.f);
    v[3] = fmaxf(bf2f((unsigned short)(zr.y >> 16)) + acc[3], 0.f);
    v[4] = fmaxf(bf2f((unsigned short)(zr.z & 0xffff)) + acc[4], 0.f);
    v[5] = fmaxf(bf2f((unsigned short)(zr.z >> 16)) + acc[5], 0.f);
    v[6] = fmaxf(bf2f((unsigned short)(zr.w & 0xffff)) + acc[6], 0.f);
    v[7] = fmaxf(bf2f((unsigned short)(zr.w >> 16)) + acc[7], 0.f);

    uint4 pk;
    pk.x = (unsigned int)f2bf(v[0]) | ((unsigned int)f2bf(v[1]) << 16);
    pk.y = (unsigned int)f2bf(v[2]) | ((unsigned int)f2bf(v[3]) << 16);
    pk.z = (unsigned int)f2bf(v[4]) | ((unsigned int)f2bf(v[5]) << 16);
    pk.w = (unsigned int)f2bf(v[6]) | ((unsigned int)f2bf(v[7]) << 16);
    *(uint4*)(hout + (size_t)node * DIM + c8) = pk;
}

// ---------------------------------------------------------------------------
// aggr_row_final: same structure, f32 output.
// ---------------------------------------------------------------------------
__global__ __launch_bounds__(256) void aggr_row_final(
    const unsigned short* __restrict__ z,    // z2
    const unsigned short* __restrict__ zi,   // zi2
    const float* __restrict__ alpha,
    const int* __restrict__ edge_src,
    float* __restrict__ out_f32)
{
    __shared__ float alpha_s[256];
    __shared__ int   src_s[256];

    const int t = threadIdx.x;
    const int base = blockIdx.x * 16;

    {
        int e0 = base * DEG + t;
        alpha_s[t] = alpha[e0];
        src_s[t]   = edge_src[e0];
    }
    __syncthreads();

    const int nl = t >> 4;
    const int j  = t & 15;
    const int node = base + nl;
    const int c8 = j * 8;
    const unsigned short* zc = z + c8;

    float acc[8] = {};
#pragma unroll
    for (int e = 0; e < DEG; e++) {
        int   sj = src_s[nl * 16 + e];
        float a  = alpha_s[nl * 16 + e];
        uint4 r = *(const uint4*)(zc + (size_t)sj * DIM);
        acc[0] += a * bf2f((unsigned short)(r.x & 0xffff));
        acc[1] += a * bf2f((unsigned short)(r.x >> 16));
        acc[2] += a * bf2f((unsigned short)(r.y & 0xffff));
        acc[3] += a * bf2f((unsigned short)(r.y >> 16));
        acc[4] += a * bf2f((unsigned short)(r.z & 0xffff));
        acc[5] += a * bf2f((unsigned short)(r.z >> 16));
        acc[6] += a * bf2f((unsigned short)(r.w & 0xffff));
        acc[7] += a * bf2f((unsigned short)(r.w >> 16));
    }

    uint4 zr = *(const uint4*)(zi + (size_t)node * DIM + c8);
    float* op = out_f32 + (size_t)node * DIM + c8;
    f32x4 o0, o1;
    o0[0] = fmaxf(bf2f((unsigned short)(zr.x & 0xffff)) + acc[0], 0.f);
    o0[1] = fmaxf(bf2f((unsigned short)(zr.x >> 16)) + acc[1], 0.f);
    o0[2] = fmaxf(bf2f((unsigned short)(zr.y & 0xffff)) + acc[2], 0.f);
    o0[3] = fmaxf(bf2f((unsigned short)(zr.y >> 16)) + acc[3], 0.f);
    o1[0] = fmaxf(bf2f((unsigned short)(zr.z & 0xffff)) + acc[4], 0.f);
    o1[1] = fmaxf(bf2f((unsigned short)(zr.z >> 16)) + acc[5], 0.f);
    o1[2] = fmaxf(bf2f((unsigned short)(zr.w & 0xffff)) + acc[6], 0.f);
    o1[3] = fmaxf(bf2f((unsigned short)(zr.w >> 16)) + acc[7], 0.f);
    __builtin_nontemporal_store(o0, (f32x4*)op);
    __builtin_nontemporal_store(o1, (f32x4*)(op + 4));
}

// ---------------------------------------------------------------------------
extern "C" void kernel_launch(void* const* d_in, const int* in_sizes, int n_in,
                              void* d_out, int out_size, void* d_ws, size_t ws_size,
                              hipStream_t stream) {
    const float* attr     = (const float*)d_in[0];
    const float* edge_d   = (const float*)d_in[1];
    const float* W_V1     = (const float*)d_in[2];
    const float* W_W1     = (const float*)d_in[3];
    const float* W_U1     = (const float*)d_in[4];
    const float* W_a1     = (const float*)d_in[5];
    const float* W_V2     = (const float*)d_in[6];
    const float* W_W2     = (const float*)d_in[7];
    const float* W_U2     = (const float*)d_in[8];
    const float* W_a2     = (const float*)d_in[9];
    const int*   edge_src = (const int*)d_in[10];

    float* out = (float*)d_out;

    char* ws = (char*)d_ws;
    unsigned short* z1    = (unsigned short*)ws;                       // 25.6 MB
    unsigned short* zi1   = (unsigned short*)(ws + 26u * 1024 * 1024); // 25.6 MB
    unsigned short* h1    = (unsigned short*)(ws + 52u * 1024 * 1024); // 25.6 MB
    unsigned short* Wc1   = (unsigned short*)(ws + 78u * 1024 * 1024);
    unsigned short* Wc2   = (unsigned short*)(ws + 79u * 1024 * 1024);
    float* s_src0         = (float*)(ws + 80u * 1024 * 1024);
    float* s_src1         = (float*)(ws + 81u * 1024 * 1024);
    float* s_dst0         = (float*)(ws + 82u * 1024 * 1024);
    float* s_dst1         = (float*)(ws + 83u * 1024 * 1024);
    float* alphaA         = (float*)(ws + 84u * 1024 * 1024);          // 6.4 MB
    // z2/zi2 overlay z1/zi1 (strictly sequential dependencies)
    unsigned short* z2  = z1;
    unsigned short* zi2 = zi1;

    prep_w<<<256, 256, 0, stream>>>(W_W1, W_U1, W_W2, W_U2, Wc1, Wc2);

    // ---- layer 1 ----
    dense_tile<<<DGRID, 256, 0, stream>>>(attr, Wc1, W_a1, z1, zi1,
                                          s_src0, s_src1, s_dst0, s_dst1);

    alpha_k<<<6250, 256, 0, stream>>>(s_src0, s_src1, s_dst0, s_dst1,
                                      edge_d, edge_src, W_V1, W_a1, alphaA);

    aggr_row<<<6250, 256, 0, stream>>>(z1, zi1, alphaA, edge_src, h1);

    // ---- layer 2 ----
    dense_tile_b<<<DGRID, 256, 0, stream>>>(h1, Wc2, W_a2, z2, zi2,
                                            s_src0, s_src1, s_dst0, s_dst1);

    alpha_k<<<6250, 256, 0, stream>>>(s_src0, s_src1, s_dst0, s_dst1,
                                      edge_d, edge_src, W_V2, W_a2, alphaA);

    aggr_row_final<<<6250, 256, 0, stream>>>(z2, zi2, alphaA, edge_src, out);
}